// Round 11
// baseline (1320.135 us; speedup 1.0000x reference)
//
#include <hip/hip_runtime.h>
#include <hip/hip_fp16.h>
#include <math.h>

typedef __bf16   bf16x8 __attribute__((ext_vector_type(8)));
typedef _Float16 f16x8  __attribute__((ext_vector_type(8)));
typedef float    f32x4  __attribute__((ext_vector_type(4)));
typedef float    f32x16 __attribute__((ext_vector_type(16)));

#define AH  264              // act plane stride (bf16)
#define TOT 589824           // staged weight elems (hi); lo at +TOT

// staged ws layout (bf16, [n][k] transposed, zero-padded K tails)
#define OFF_W0T   0          // [256][64]
#define OFF_WHT   16384      // 4 x [256][256]
#define OFF_W5AT  278528     // [256][256]
#define OFF_W5BT  344064     // [256][64]
#define OFF_W6T   360448     // [256][256]
#define OFF_W7T   425984     // [256][256]
#define OFF_WFT   491520     // [256][256]
#define OFF_WMAT  557056     // [128][256]

__global__ void prep_weights(const float* __restrict__ W0, const float* __restrict__ Wh,
                             const float* __restrict__ W5, const float* __restrict__ W6,
                             const float* __restrict__ W7, const float* __restrict__ Wf,
                             const float* __restrict__ Wm, __bf16* __restrict__ ws) {
  int idx = blockIdx.x * blockDim.x + threadIdx.x;
  if (idx >= TOT) return;
  float v = 0.f;
  if (idx < OFF_WHT)        { int j = idx;            int n=j>>6, k=j&63;   v = (k<60)? W0[k*256+n] : 0.f; }
  else if (idx < OFF_W5AT)  { int j = idx - OFF_WHT;  int i=j>>16, r=j&65535, n=r>>8, k=r&255; v = Wh[i*65536+k*256+n]; }
  else if (idx < OFF_W5BT)  { int j = idx - OFF_W5AT; int n=j>>8, k=j&255;  v = W5[k*256+n]; }
  else if (idx < OFF_W6T)   { int j = idx - OFF_W5BT; int n=j>>6, k=j&63;   v = (k<60)? W5[(256+k)*256+n] : 0.f; }
  else if (idx < OFF_W7T)   { int j = idx - OFF_W6T;  int n=j>>8, k=j&255;  v = W6[k*256+n]; }
  else if (idx < OFF_WFT)   { int j = idx - OFF_W7T;  int n=j>>8, k=j&255;  v = W7[k*256+n]; }
  else if (idx < OFF_WMAT)  { int j = idx - OFF_WFT;  int n=j>>8, k=j&255;  v = Wf[k*256+n]; }
  else                      { int j = idx - OFF_WMAT; int n=j>>8, k=j&255;  v = Wm[k*128+n]; }
  __bf16 hi = (__bf16)v;
  ws[idx] = hi;
  ws[TOT + idx] = (__bf16)(v - (float)hi);
}

#define MFMA16(A,B,C) __builtin_amdgcn_mfma_f32_16x16x32_bf16((A),(B),(C),0,0,0)
#define MFMA32(A,B,C) __builtin_amdgcn_mfma_f32_32x32x16_bf16((A),(B),(C),0,0,0)

// ======== HALF=1 layer on 32x32x16 MFMA ========
// Halves act-LDS reads, weight loads, and MFMA instruction count per MAC vs the
// 16x16x32 structure (A-frag covers 32rows x 16k per wave-kilobyte vs 16x32) --
// attacks the issue-side pressure of this latency-bound kernel. Register budget
// IDENTICAL to the proven R3 shape: acc 32 (2x f32x16) + weight A/B dbuf 32 +
// act <=16 live. Fragment maps: A row=lane&31, k=(lane>>5)*8+j (same K-doubling
// pattern as the verified 16x16x32 map); B col=lane&31 mirrored; C/D per
// HW-verified m74/m101: col=lane&31, row=(reg&3)+8*(reg>>2)+4*(lane>>5).
// MT=2: wave = all 64 rows x 32 cols at nBase=wave*32      (N=256 layers)
// MT=1: wave = one 32x32 tile, mBase=(wave>>2)*32, nBase=(wave&3)*32 (Wm,N=128)
// Per-element accumulation order: kc asc, s asc; a_h*b_h, a_h*b_l, a_l*b_h.
template<int MT>
__device__ __forceinline__ void layer32(__bf16* aHi, __bf16* aLo, const __half* pxh,
    const __bf16* __restrict__ wHi, const __bf16* __restrict__ wLo, int kStr, int nkc,
    const __bf16* __restrict__ xHi, const __bf16* __restrict__ xLo,  // px weights or null
    const float* __restrict__ bias, const float* __restrict__ pdW,
    bool relu, int tid) {
  const int wave = tid >> 6, lane = tid & 63;
  const int l31 = lane & 31, kh = lane >> 5;         // kh in {0,1}
  const int mBase = (MT == 2) ? 0 : ((wave >> 2) * 32);
  const int nBase = (MT == 2) ? (wave * 32) : ((wave & 3) * 32);
  f32x16 acc[MT];
#pragma unroll
  for (int mt = 0; mt < MT; ++mt)
#pragma unroll
    for (int e = 0; e < 16; ++e) acc[mt][e] = 0.f;

  const int kb0 = kh * 8;                            // per-lane k offset in a 16-k chunk
  const int wr  = (nBase + l31) * kStr + kb0;        // weight lane base
  const int ar  = (mBase + l31) * AH + kb0;          // act lane base (m-tile 0)

  if (nkc >= 2) {                                    // act part (K = nkc*32, nkc even)
    bf16x8 bhA[2], blA[2], bhB[2], blB[2];           // [sub-k]
#pragma unroll
    for (int s = 0; s < 2; ++s) {                    // preload kc=0 -> A
      bhA[s] = *(const bf16x8*)(wHi + wr + s*16);
      blA[s] = *(const bf16x8*)(wLo + wr + s*16);
    }
    for (int kc = 0; kc < nkc; kc += 2) {
#pragma unroll
      for (int s = 0; s < 2; ++s) {                  // prefetch kc+1 -> B
        bhB[s] = *(const bf16x8*)(wHi + wr + (kc+1)*32 + s*16);
        blB[s] = *(const bf16x8*)(wLo + wr + (kc+1)*32 + s*16);
      }
#pragma unroll
      for (int s = 0; s < 2; ++s) {                  // compute kc with A
        const int ko = kc*32 + s*16;
        bf16x8 a0h = *(const bf16x8*)(aHi + ar + ko);
        bf16x8 a0l = *(const bf16x8*)(aLo + ar + ko);
        bf16x8 a1h, a1l;
        if (MT == 2) {
          a1h = *(const bf16x8*)(aHi + ar + 32*AH + ko);
          a1l = *(const bf16x8*)(aLo + ar + 32*AH + ko);
        }
        __builtin_amdgcn_s_setprio(1);
        acc[0] = MFMA32(a0h, bhA[s], acc[0]);
        if (MT == 2) acc[1] = MFMA32(a1h, bhA[s], acc[1]);
        acc[0] = MFMA32(a0h, blA[s], acc[0]);
        if (MT == 2) acc[1] = MFMA32(a1h, blA[s], acc[1]);
        acc[0] = MFMA32(a0l, bhA[s], acc[0]);
        if (MT == 2) acc[1] = MFMA32(a1l, bhA[s], acc[1]);
        __builtin_amdgcn_s_setprio(0);
      }
      if (kc + 2 < nkc) {                            // prefetch kc+2 -> A
#pragma unroll
        for (int s = 0; s < 2; ++s) {
          bhA[s] = *(const bf16x8*)(wHi + wr + (kc+2)*32 + s*16);
          blA[s] = *(const bf16x8*)(wLo + wr + (kc+2)*32 + s*16);
        }
      }
#pragma unroll
      for (int s = 0; s < 2; ++s) {                  // compute kc+1 with B
        const int ko = (kc+1)*32 + s*16;
        bf16x8 a0h = *(const bf16x8*)(aHi + ar + ko);
        bf16x8 a0l = *(const bf16x8*)(aLo + ar + ko);
        bf16x8 a1h, a1l;
        if (MT == 2) {
          a1h = *(const bf16x8*)(aHi + ar + 32*AH + ko);
          a1l = *(const bf16x8*)(aLo + ar + 32*AH + ko);
        }
        __builtin_amdgcn_s_setprio(1);
        acc[0] = MFMA32(a0h, bhB[s], acc[0]);
        if (MT == 2) acc[1] = MFMA32(a1h, bhB[s], acc[1]);
        acc[0] = MFMA32(a0h, blB[s], acc[0]);
        if (MT == 2) acc[1] = MFMA32(a1h, blB[s], acc[1]);
        acc[0] = MFMA32(a0l, bhB[s], acc[0]);
        if (MT == 2) acc[1] = MFMA32(a1l, bhB[s], acc[1]);
        __builtin_amdgcn_s_setprio(0);
      }
    }
  }
  if (xHi) {                                         // px part, K=64 (zero-padded tail)
#pragma unroll
    for (int sk = 0; sk < 4; ++sk) {
      const int ko = sk * 16;
      bf16x8 bh = *(const bf16x8*)(xHi + (nBase + l31)*64 + kb0 + ko);
      bf16x8 bl = *(const bf16x8*)(xLo + (nBase + l31)*64 + kb0 + ko);
      bf16x8 ah[MT], al[MT];
#pragma unroll
      for (int mt = 0; mt < MT; ++mt) {
        const f16x8 pv = *(const f16x8*)((const _Float16*)pxh + (mBase + mt*32 + l31)*64 + kb0 + ko);
#pragma unroll
        for (int j = 0; j < 8; ++j) {
          float v = (float)pv[j];
          __bf16 h = (__bf16)v;
          ah[mt][j] = h;
          al[mt][j] = (__bf16)(v - (float)h);
        }
      }
      __builtin_amdgcn_s_setprio(1);
#pragma unroll
      for (int mt = 0; mt < MT; ++mt) {
        acc[mt] = MFMA32(ah[mt], bh, acc[mt]);
        acc[mt] = MFMA32(ah[mt], bl, acc[mt]);
        acc[mt] = MFMA32(al[mt], bh, acc[mt]);
      }
      __builtin_amdgcn_s_setprio(0);
    }
  }
  __syncthreads();                 // all reads of act complete
  {
    const int col = nBase + l31;
    const float bv = bias[col] + (pdW ? pdW[col] : 0.f);
#pragma unroll
    for (int mt = 0; mt < MT; ++mt)
#pragma unroll
      for (int r = 0; r < 16; ++r) {
        const int row = mBase + mt*32 + (r & 3) + 8*(r >> 2) + 4*kh;
        float v = acc[mt][r] + bv;
        if (relu) v = fmaxf(v, 0.f);
        __bf16 h = (__bf16)v;
        aHi[row*AH + col] = h;
        aLo[row*AH + col] = (__bf16)(v - (float)h);
      }
  }
  __syncthreads();
}

// ======== HALF=0 fallback layer (unchanged, 16x16x32) ========
template<int NT>
__device__ __forceinline__ void mfma_layer(__bf16* aHi, __bf16* aLo, const __half* pxh,
    const __bf16* __restrict__ wHi, const __bf16* __restrict__ wLo, int kStr, int nkc,
    const __bf16* __restrict__ xHi, const __bf16* __restrict__ xLo,
    const float* __restrict__ bias, const float* __restrict__ pdW,
    bool relu, int tid) {
  const int wave = tid >> 6, lane = tid & 63;
  const int lm = lane & 15, kq = lane >> 4;
  const int mBase = (wave >> 2) * 64;
  const int nBase = (wave & 3) * (NT * 16);
  f32x4 acc[4][NT];
#pragma unroll
  for (int mt = 0; mt < 4; ++mt)
#pragma unroll
    for (int nt = 0; nt < NT; ++nt)
#pragma unroll
      for (int e = 0; e < 4; ++e) acc[mt][nt][e] = 0.f;

  if (nkc >= 2) {
    for (int kc = 0; kc < nkc; ++kc) {
      const int kb = kc*32 + kq*8;
      bf16x8 ah[4], al[4], bh[NT], bl[NT];
#pragma unroll
      for (int mt = 0; mt < 4; ++mt) {
        const int off = (mBase + mt*16 + lm)*AH + kb;
        ah[mt] = *(const bf16x8*)(aHi + off);
        al[mt] = *(const bf16x8*)(aLo + off);
      }
#pragma unroll
      for (int nt = 0; nt < NT; ++nt) {
        const int ro = (nBase + nt*16 + lm)*kStr + kb;
        bh[nt] = *(const bf16x8*)(wHi + ro);
        bl[nt] = *(const bf16x8*)(wLo + ro);
      }
#pragma unroll
      for (int p = 0; p < 3; ++p)
#pragma unroll
        for (int mt = 0; mt < 4; ++mt)
#pragma unroll
          for (int nt = 0; nt < NT; ++nt)
            acc[mt][nt] = __builtin_amdgcn_mfma_f32_16x16x32_bf16(
                (p == 2) ? al[mt] : ah[mt],
                (p == 1) ? bl[nt] : bh[nt],
                acc[mt][nt], 0, 0, 0);
    }
  }
  if (xHi) {
#pragma unroll
    for (int kc = 0; kc < 2; ++kc) {
      const int kb = kc*32 + kq*8;
      bf16x8 bh[NT], bl[NT];
#pragma unroll
      for (int nt = 0; nt < NT; ++nt) {
        const int ro = (nBase + nt*16 + lm)*64 + kb;
        bh[nt] = *(const bf16x8*)(xHi + ro);
        bl[nt] = *(const bf16x8*)(xLo + ro);
      }
#pragma unroll
      for (int mp = 0; mp < 2; ++mp) {
        bf16x8 ah[2], al[2];
#pragma unroll
        for (int i = 0; i < 2; ++i) {
          const f16x8 pv = *(const f16x8*)((const _Float16*)pxh + (mBase + (2*mp+i)*16 + lm)*64 + kb);
#pragma unroll
          for (int j = 0; j < 8; ++j) {
            float v = (float)pv[j];
            __bf16 h = (__bf16)v;
            ah[i][j] = h;
            al[i][j] = (__bf16)(v - (float)h);
          }
        }
#pragma unroll
        for (int nt = 0; nt < NT; ++nt) {
          acc[2*mp  ][nt] = MFMA16(ah[0], bh[nt], acc[2*mp  ][nt]);
          acc[2*mp+1][nt] = MFMA16(ah[1], bh[nt], acc[2*mp+1][nt]);
          acc[2*mp  ][nt] = MFMA16(ah[0], bl[nt], acc[2*mp  ][nt]);
          acc[2*mp+1][nt] = MFMA16(ah[1], bl[nt], acc[2*mp+1][nt]);
          acc[2*mp  ][nt] = MFMA16(al[0], bh[nt], acc[2*mp  ][nt]);
          acc[2*mp+1][nt] = MFMA16(al[1], bh[nt], acc[2*mp+1][nt]);
        }
      }
    }
  }
  __syncthreads();
#pragma unroll
  for (int mt = 0; mt < 4; ++mt)
#pragma unroll
    for (int nt = 0; nt < NT; ++nt) {
      const int col = nBase + nt*16 + lm;
      float bv = bias[col] + (pdW ? pdW[col] : 0.f);
#pragma unroll
      for (int r = 0; r < 4; ++r) {
        const int row = mBase + mt*16 + kq*4 + r;
        float v = acc[mt][nt][r] + bv;
        if (relu) v = fmaxf(v, 0.f);
        __bf16 h = (__bf16)v;
        aHi[row*AH + col] = h;
        aLo[row*AH + col] = (__bf16)(v - (float)h);
      }
    }
  __syncthreads();
}

// HALF=1: blockIdx = ray*2 + half, covers samples [half*64, half*64+64)
// HALF=0: blockIdx = ray, covers all 128 samples (fallback config)
template<int HALF>
__global__ __launch_bounds__(512, 4)
void nerf_main(
    const float* __restrict__ ro, const float* __restrict__ rd, const float* __restrict__ tin,
    const float* __restrict__ b0, const float* __restrict__ bh,
    const float* __restrict__ b5, const float* __restrict__ b6,
    const float* __restrict__ b7,
    const float* __restrict__ Wsig, const float* __restrict__ bs,
    const float* __restrict__ bfb,
    const float* __restrict__ Wm, const float* __restrict__ bm,
    const float* __restrict__ Wr, const float* __restrict__ br,
    const __bf16* __restrict__ wsHi, const __bf16* __restrict__ wsLo,
    float* __restrict__ part, float* __restrict__ out) {
  constexpr int M = HALF ? 64 : 128;
  __shared__ __align__(16) __bf16 aHi[M * AH];
  __shared__ __align__(16) __bf16 aLo[M * AH];
  __shared__ __align__(16) unsigned char pxred[M * 128];  // pxh (M*64 halves) / red union
  __shared__ __align__(16) float  pdBuf[24];
  __shared__ __align__(16) float  pdW[128];
  __shared__ __align__(16) float  tBuf[M + 4];
  __shared__ __align__(16) float  sigBuf[M];
  __shared__ __align__(16) float  rgbBuf[M * 3];

  __half* pxh = (__half*)pxred;
  float*  red = (float*)pxred;         // used after pxh dead (sigma head onward)

  const int blk  = blockIdx.x;
  const int ray  = HALF ? (blk >> 1) : blk;
  const int S    = HALF ? (blk & 1) * 64 : 0;
  const int tid  = threadIdx.x;

  // ---- positional encodings ----
  if (tid < M) {
    const int m = tid;
    float tv = tin[ray*128 + S + m];
    tBuf[m] = tv;
    float xs[3];
#pragma unroll
    for (int c = 0; c < 3; ++c) xs[c] = ro[ray*3 + c] + tv * rd[ray*3 + c];
#pragma unroll
    for (int i = 0; i < 10; ++i)
#pragma unroll
      for (int c = 0; c < 3; ++c) {
        float a = ldexpf(xs[c], i);                 // sin(2^i*pi*x) = sinpi(2^i*x)
        pxh[m*64 + i*6 + c]     = __float2half(sinpif(a));
        pxh[m*64 + i*6 + 3 + c] = __float2half(cospif(a));
      }
#pragma unroll
    for (int j = 60; j < 64; ++j) pxh[m*64 + j] = __float2half(0.f);
  } else if (tid < M + 24) {
    int j = tid - M;
    int i = j / 6, r = j % 6;
    float a = ldexpf(rd[ray*3 + (r % 3)], i);
    pdBuf[j] = (r < 3) ? sinpif(a) : cospif(a);
  } else if (tid == M + 24) {
    tBuf[M] = (S + M < 128) ? tin[ray*128 + S + M] : 0.f;   // next-t for last delta
  }
  __syncthreads();
  if (tid >= 256 && tid < 384) {       // pdW[c] = sum_j pd[j]*Wm[256+j][c]
    int c = tid - 256;
    float s = 0.f;
#pragma unroll
    for (int j = 0; j < 24; ++j) s += pdBuf[j] * Wm[(256 + j)*128 + c];
    pdW[c] = s;
  }
  __syncthreads();

  // ---- trunk ----
  if constexpr (HALF) {
    layer32<2>(aHi, aLo, pxh, nullptr, nullptr, 0, 0,
               wsHi + OFF_W0T, wsLo + OFF_W0T, b0, nullptr, true, tid);
    for (int i = 0; i < 4; ++i)
      layer32<2>(aHi, aLo, pxh, wsHi + OFF_WHT + i*65536, wsLo + OFF_WHT + i*65536, 256, 8,
                 nullptr, nullptr, bh + i*256, nullptr, true, tid);
    layer32<2>(aHi, aLo, pxh, wsHi + OFF_W5AT, wsLo + OFF_W5AT, 256, 8,
               wsHi + OFF_W5BT, wsLo + OFF_W5BT, b5, nullptr, true, tid);
    layer32<2>(aHi, aLo, pxh, wsHi + OFF_W6T, wsLo + OFF_W6T, 256, 8,
               nullptr, nullptr, b6, nullptr, true, tid);
    layer32<2>(aHi, aLo, pxh, wsHi + OFF_W7T, wsLo + OFF_W7T, 256, 8,
               nullptr, nullptr, b7, nullptr, true, tid);
  } else {
    mfma_layer<4>(aHi, aLo, pxh, nullptr, nullptr, 0, 0,
                  wsHi + OFF_W0T, wsLo + OFF_W0T, b0, nullptr, true, tid);
    for (int i = 0; i < 4; ++i)
      mfma_layer<4>(aHi, aLo, pxh, wsHi + OFF_WHT + i*65536, wsLo + OFF_WHT + i*65536, 256, 8,
                    nullptr, nullptr, bh + i*256, nullptr, true, tid);
    mfma_layer<4>(aHi, aLo, pxh, wsHi + OFF_W5AT, wsLo + OFF_W5AT, 256, 8,
                  wsHi + OFF_W5BT, wsLo + OFF_W5BT, b5, nullptr, true, tid);
    mfma_layer<4>(aHi, aLo, pxh, wsHi + OFF_W6T, wsLo + OFF_W6T, 256, 8,
                  nullptr, nullptr, b6, nullptr, true, tid);
    mfma_layer<4>(aHi, aLo, pxh, wsHi + OFF_W7T, wsLo + OFF_W7T, 256, 8,
                  nullptr, nullptr, b7, nullptr, true, tid);
  }

  // sigma = relu(h @ Ws + bs)   (pxh now dead -> red)
  {
    constexpr int TPS = 512 / M;       // threads per sample (8 or 4)
    const int m = tid / TPS, q = tid % TPS;
    const int kn = 256 / TPS;
    float s = 0.f;
    for (int k8 = q*kn; k8 < q*kn + kn; k8 += 8) {
      bf16x8 vh = *(const bf16x8*)(aHi + m*AH + k8);
      bf16x8 vl = *(const bf16x8*)(aLo + m*AH + k8);
#pragma unroll
      for (int j = 0; j < 8; ++j) s += ((float)vh[j] + (float)vl[j]) * Wsig[k8 + j];
    }
    red[tid] = s;
    __syncthreads();
    if (tid < M) {
      float sm = bs[0];
#pragma unroll
      for (int j = 0; j < TPS; ++j) sm += red[TPS*tid + j];
      sigBuf[tid] = fmaxf(sm, 0.f);
    }
    __syncthreads();
  }

  // feat = h @ Wf + bf (no relu)
  if constexpr (HALF)
    layer32<2>(aHi, aLo, nullptr, wsHi + OFF_WFT, wsLo + OFF_WFT, 256, 8,
               nullptr, nullptr, bfb, nullptr, false, tid);
  else
    mfma_layer<4>(aHi, aLo, nullptr, wsHi + OFF_WFT, wsLo + OFF_WFT, 256, 8,
                  nullptr, nullptr, bfb, nullptr, false, tid);

  // h2 = relu([feat, pd] @ Wm + bm), N=128 (pd folded via pdW)
  if constexpr (HALF)
    layer32<1>(aHi, aLo, nullptr, wsHi + OFF_WMAT, wsLo + OFF_WMAT, 256, 8,
               nullptr, nullptr, bm, pdW, true, tid);
  else
    mfma_layer<2>(aHi, aLo, nullptr, wsHi + OFF_WMAT, wsLo + OFF_WMAT, 256, 8,
                  nullptr, nullptr, bm, pdW, true, tid);

  // rgb = sigmoid(h2 @ Wr + br)
  {
    constexpr int TPS = 512 / M;
    const int m = tid / TPS, q = tid % TPS;
    const int kn = 128 / TPS;
    float r0s = 0.f, r1s = 0.f, r2s = 0.f;
    for (int k8 = q*kn; k8 < q*kn + kn; k8 += 8) {
      bf16x8 vh = *(const bf16x8*)(aHi + m*AH + k8);
      bf16x8 vl = *(const bf16x8*)(aLo + m*AH + k8);
#pragma unroll
      for (int j = 0; j < 8; ++j) {
        float hv = (float)vh[j] + (float)vl[j];
        r0s += hv * Wr[(k8 + j)*3 + 0];
        r1s += hv * Wr[(k8 + j)*3 + 1];
        r2s += hv * Wr[(k8 + j)*3 + 2];
      }
    }
    red[tid] = r0s; red[512 + tid] = r1s; red[1024 + tid] = r2s;
    __syncthreads();
    if (tid < M) {
#pragma unroll
      for (int c = 0; c < 3; ++c) {
        float sm = br[c];
#pragma unroll
        for (int j = 0; j < TPS; ++j) sm += red[c*512 + TPS*tid + j];
        rgbBuf[tid*3 + c] = 1.f / (1.f + expf(-sm));
      }
    }
    __syncthreads();
  }

  // volume rendering: serial transmittance scan over this block's segment
  if (tid == 0) {
    float T = 1.f, c0 = 0.f, c1 = 0.f, c2 = 0.f, wsum = 0.f;
    for (int m = 0; m < M; ++m) {
      float delta = (S + m < 127) ? (tBuf[m + 1] - tBuf[m]) : 1e8f;
      float e = expf(-sigBuf[m] * delta);
      float w = T * (1.f - e);
      c0 += w * rgbBuf[m*3 + 0];
      c1 += w * rgbBuf[m*3 + 1];
      c2 += w * rgbBuf[m*3 + 2];
      wsum += w;
      T *= e;
    }
    if (HALF) {
      float* p = part + blk*5;
      p[0] = c0; p[1] = c1; p[2] = c2; p[3] = wsum; p[4] = T;
    } else {
      float bg = 1.f - wsum;           // C_BG = (1,1,1)
      out[ray*3 + 0] = c0 + bg;
      out[ray*3 + 1] = c1 + bg;
      out[ray*3 + 2] = c2 + bg;
    }
  }
}

__global__ void combine(const float* __restrict__ part, float* __restrict__ out) {
  int r = blockIdx.x * blockDim.x + threadIdx.x;
  if (r >= 2048) return;
  const float* p0 = part + (2*r)*5;
  const float* p1 = p0 + 5;
  float T0 = p0[4];
  float wsum = p0[3] + T0 * p1[3];
  float bg = 1.f - wsum;               // C_BG = (1,1,1)
#pragma unroll
  for (int c = 0; c < 3; ++c)
    out[r*3 + c] = p0[c] + T0 * p1[c] + bg;
}

extern "C" void kernel_launch(void* const* d_in, const int* in_sizes, int n_in,
                              void* d_out, int out_size, void* d_ws, size_t ws_size,
                              hipStream_t stream) {
  const float* ro  = (const float*)d_in[0];
  const float* rd  = (const float*)d_in[1];
  const float* t   = (const float*)d_in[2];
  const float* W0  = (const float*)d_in[3];
  const float* b0  = (const float*)d_in[4];
  const float* Wh  = (const float*)d_in[5];
  const float* bh  = (const float*)d_in[6];
  const float* W5  = (const float*)d_in[7];
  const float* b5  = (const float*)d_in[8];
  const float* W6  = (const float*)d_in[9];
  const float* b6  = (const float*)d_in[10];
  const float* W7  = (const float*)d_in[11];
  const float* b7  = (const float*)d_in[12];
  const float* Wsg = (const float*)d_in[13];
  const float* bs  = (const float*)d_in[14];
  const float* Wf  = (const float*)d_in[15];
  const float* bfb = (const float*)d_in[16];
  const float* Wm  = (const float*)d_in[17];
  const float* bm  = (const float*)d_in[18];
  const float* Wr  = (const float*)d_in[19];
  const float* br  = (const float*)d_in[20];
  float* out = (float*)d_out;

  __bf16* wsHi = (__bf16*)d_ws;                     // 2*TOT bf16 = 2.36 MB (proven)
  __bf16* wsLo = wsHi + TOT;
  float*  part = (float*)((char*)d_ws + (size_t)2 * TOT * 2);   // 4096*5 floats = 80 KB

  const size_t needSplit = (size_t)2 * TOT * 2 + (size_t)4096 * 5 * 4;

  prep_weights<<<(TOT + 255)/256, 256, 0, stream>>>(W0, Wh, W5, W6, W7, Wf, Wm, wsHi);
  if (ws_size >= needSplit) {
    nerf_main<1><<<4096, 512, 0, stream>>>(ro, rd, t, b0, bh, b5, b6, b7,
                                           Wsg, bs, bfb, Wm, bm, Wr, br,
                                           wsHi, wsLo, part, out);
    combine<<<8, 256, 0, stream>>>(part, out);
  } else {
    nerf_main<0><<<2048, 512, 0, stream>>>(ro, rd, t, b0, bh, b5, b6, b7,
                                           Wsg, bs, bfb, Wm, bm, Wr, br,
                                           wsHi, wsLo, part, out);
  }
}

// Round 12
// 1313.694 us; speedup vs baseline: 1.0049x; 1.0049x over previous
//
#include <hip/hip_runtime.h>
#include <hip/hip_fp16.h>
#include <math.h>

typedef __bf16   bf16x8 __attribute__((ext_vector_type(8)));
typedef _Float16 f16x8  __attribute__((ext_vector_type(8)));
typedef float    f32x4  __attribute__((ext_vector_type(4)));

#define AH  264              // act plane stride (bf16)
#define TOT 589824           // staged weight elems (hi); lo at +TOT

// staged ws layout (bf16, [n][k] transposed, zero-padded K tails)
#define OFF_W0T   0          // [256][64]
#define OFF_WHT   16384      // 4 x [256][256]
#define OFF_W5AT  278528     // [256][256]
#define OFF_W5BT  344064     // [256][64]
#define OFF_W6T   360448     // [256][256]
#define OFF_W7T   425984     // [256][256]
#define OFF_WFT   491520     // [256][256]
#define OFF_WMAT  557056     // [128][256]

__global__ void prep_weights(const float* __restrict__ W0, const float* __restrict__ Wh,
                             const float* __restrict__ W5, const float* __restrict__ W6,
                             const float* __restrict__ W7, const float* __restrict__ Wf,
                             const float* __restrict__ Wm, __bf16* __restrict__ ws) {
  int idx = blockIdx.x * blockDim.x + threadIdx.x;
  if (idx >= TOT) return;
  float v = 0.f;
  if (idx < OFF_WHT)        { int j = idx;            int n=j>>6, k=j&63;   v = (k<60)? W0[k*256+n] : 0.f; }
  else if (idx < OFF_W5AT)  { int j = idx - OFF_WHT;  int i=j>>16, r=j&65535, n=r>>8, k=r&255; v = Wh[i*65536+k*256+n]; }
  else if (idx < OFF_W5BT)  { int j = idx - OFF_W5AT; int n=j>>8, k=j&255;  v = W5[k*256+n]; }
  else if (idx < OFF_W6T)   { int j = idx - OFF_W5BT; int n=j>>6, k=j&63;   v = (k<60)? W5[(256+k)*256+n] : 0.f; }
  else if (idx < OFF_W7T)   { int j = idx - OFF_W6T;  int n=j>>8, k=j&255;  v = W6[k*256+n]; }
  else if (idx < OFF_WFT)   { int j = idx - OFF_W7T;  int n=j>>8, k=j&255;  v = W7[k*256+n]; }
  else if (idx < OFF_WMAT)  { int j = idx - OFF_WFT;  int n=j>>8, k=j&255;  v = Wf[k*256+n]; }
  else                      { int j = idx - OFF_WMAT; int n=j>>8, k=j&255;  v = Wm[k*128+n]; }
  __bf16 hi = (__bf16)v;
  ws[idx] = hi;
  ws[TOT + idx] = (__bf16)(v - (float)hi);
}

#define MFMA16(A,B,C) __builtin_amdgcn_mfma_f32_16x16x32_bf16((A),(B),(C),0,0,0)

// ---- split-bf16 3-pass MFMA layer; act = hi/lo bf16 planes in LDS ----
// R10 champion structure (1255 us) + DUAL ACCUMULATOR BANKS: acc gets the h*h
// pass (depth-1 chains), accQ gets h*l + l*h (depth-2) -- max MFMA dependency
// depth per s-step 3 -> 2, independent chains 8 -> 16. R11 evidence: the kernel
// is MFMA-latency-sensitive (32x32's depth/latency increase cost 7% despite
// -78% conflicts). Register math: +32 regs land on the ACC side of the unified
// file (56 arch + 64 acc = 120 <= 128/wave @ 4 waves/SIMD) -- does NOT touch
// the ~64-arch-VGPR budget the allocator pins (R6/R7 spill lesson).
// Numerics: same products, re-associated fp32 sums ((Shh)+(Shl+lh)) -> ~1e-7
// relative, expected <=1 bf16 ulp on outputs. Canary: WRITE_SIZE must stay KB.
template<int NT, int HALF>
__device__ __forceinline__ void mfma_layer(__bf16* aHi, __bf16* aLo, const __half* pxh,
    const __bf16* __restrict__ wHi, const __bf16* __restrict__ wLo, int kStr, int nkc,
    const __bf16* __restrict__ xHi, const __bf16* __restrict__ xLo,  // px weights or null
    const float* __restrict__ bias, const float* __restrict__ pdW,
    bool relu, int tid) {
  const int wave = tid >> 6, lane = tid & 63;
  const int lm = lane & 15, kq = lane >> 4;
  const int mBase = HALF ? 0 : (wave >> 2) * 64;
  const int nBase = (HALF ? wave : (wave & 3)) * (NT * 16);
  f32x4 acc[4][NT];                    // h*h bank
  f32x4 accQ[4][NT];                   // h*l + l*h bank (NT<=2 path only)
#pragma unroll
  for (int mt = 0; mt < 4; ++mt)
#pragma unroll
    for (int nt = 0; nt < NT; ++nt)
#pragma unroll
      for (int e = 0; e < 4; ++e) { acc[mt][nt][e] = 0.f; if constexpr (NT <= 2) accQ[mt][nt][e] = 0.f; }

  if (nkc >= 2) {                              // act part (K = nkc*32, nkc always even)
    if constexpr (NT <= 2) {
      const int kb0 = kq * 8;
      int wr[NT];
#pragma unroll
      for (int nt = 0; nt < NT; ++nt) wr[nt] = (nBase + nt*16 + lm)*kStr + kb0;
      const int ab = (mBase + lm)*AH + kb0;
      bf16x8 bhA[NT], blA[NT], bhB[NT], blB[NT];
#pragma unroll
      for (int nt = 0; nt < NT; ++nt) {        // preload kc=0
        bhA[nt] = *(const bf16x8*)(wHi + wr[nt]);
        blA[nt] = *(const bf16x8*)(wLo + wr[nt]);
      }
      for (int kc = 0; kc < nkc; kc += 2) {
        // prefetch kc+1 weights into B while A computes
#pragma unroll
        for (int nt = 0; nt < NT; ++nt) {
          bhB[nt] = *(const bf16x8*)(wHi + wr[nt] + (kc+1)*32);
          blB[nt] = *(const bf16x8*)(wLo + wr[nt] + (kc+1)*32);
        }
#pragma unroll
        for (int mp = 0; mp < 2; ++mp) {       // compute kc with A
          const int r0 = ab + mp*32*AH + kc*32;
          bf16x8 a0h = *(const bf16x8*)(aHi + r0);
          bf16x8 a0l = *(const bf16x8*)(aLo + r0);
          bf16x8 a1h = *(const bf16x8*)(aHi + r0 + 16*AH);
          bf16x8 a1l = *(const bf16x8*)(aLo + r0 + 16*AH);
          __builtin_amdgcn_s_setprio(1);
#pragma unroll
          for (int nt = 0; nt < NT; ++nt) {
            acc [2*mp  ][nt] = MFMA16(a0h, bhA[nt], acc [2*mp  ][nt]);   // hh
            acc [2*mp+1][nt] = MFMA16(a1h, bhA[nt], acc [2*mp+1][nt]);
            accQ[2*mp  ][nt] = MFMA16(a0h, blA[nt], accQ[2*mp  ][nt]);   // hl
            accQ[2*mp+1][nt] = MFMA16(a1h, blA[nt], accQ[2*mp+1][nt]);
            accQ[2*mp  ][nt] = MFMA16(a0l, bhA[nt], accQ[2*mp  ][nt]);   // lh
            accQ[2*mp+1][nt] = MFMA16(a1l, bhA[nt], accQ[2*mp+1][nt]);
          }
          __builtin_amdgcn_s_setprio(0);
        }
        if (kc + 2 < nkc) {                    // prefetch kc+2 into A
#pragma unroll
          for (int nt = 0; nt < NT; ++nt) {
            bhA[nt] = *(const bf16x8*)(wHi + wr[nt] + (kc+2)*32);
            blA[nt] = *(const bf16x8*)(wLo + wr[nt] + (kc+2)*32);
          }
        }
#pragma unroll
        for (int mp = 0; mp < 2; ++mp) {       // compute kc+1 with B
          const int r0 = ab + mp*32*AH + (kc+1)*32;
          bf16x8 a0h = *(const bf16x8*)(aHi + r0);
          bf16x8 a0l = *(const bf16x8*)(aLo + r0);
          bf16x8 a1h = *(const bf16x8*)(aHi + r0 + 16*AH);
          bf16x8 a1l = *(const bf16x8*)(aLo + r0 + 16*AH);
          __builtin_amdgcn_s_setprio(1);
#pragma unroll
          for (int nt = 0; nt < NT; ++nt) {
            acc [2*mp  ][nt] = MFMA16(a0h, bhB[nt], acc [2*mp  ][nt]);
            acc [2*mp+1][nt] = MFMA16(a1h, bhB[nt], acc [2*mp+1][nt]);
            accQ[2*mp  ][nt] = MFMA16(a0h, blB[nt], accQ[2*mp  ][nt]);
            accQ[2*mp+1][nt] = MFMA16(a1h, blB[nt], accQ[2*mp+1][nt]);
            accQ[2*mp  ][nt] = MFMA16(a0l, bhB[nt], accQ[2*mp  ][nt]);
            accQ[2*mp+1][nt] = MFMA16(a1l, bhB[nt], accQ[2*mp+1][nt]);
          }
          __builtin_amdgcn_s_setprio(0);
        }
      }
    } else {                                   // NT=4 fallback (unused in HALF=1 runs)
      for (int kc = 0; kc < nkc; ++kc) {
        const int kb = kc*32 + kq*8;
        bf16x8 ah[4], al[4], bh[NT], bl[NT];
#pragma unroll
        for (int mt = 0; mt < 4; ++mt) {
          const int off = (mBase + mt*16 + lm)*AH + kb;
          ah[mt] = *(const bf16x8*)(aHi + off);
          al[mt] = *(const bf16x8*)(aLo + off);
        }
#pragma unroll
        for (int nt = 0; nt < NT; ++nt) {
          const int ro = (nBase + nt*16 + lm)*kStr + kb;
          bh[nt] = *(const bf16x8*)(wHi + ro);
          bl[nt] = *(const bf16x8*)(wLo + ro);
        }
#pragma unroll
        for (int p = 0; p < 3; ++p)
#pragma unroll
          for (int mt = 0; mt < 4; ++mt)
#pragma unroll
            for (int nt = 0; nt < NT; ++nt)
              acc[mt][nt] = __builtin_amdgcn_mfma_f32_16x16x32_bf16(
                  (p == 2) ? al[mt] : ah[mt],
                  (p == 1) ? bl[nt] : bh[nt],
                  acc[mt][nt], 0, 0, 0);
      }
    }
  }
  if (xHi) {                                   // px part, K=64 (zero-padded tail)
#pragma unroll
    for (int kc = 0; kc < 2; ++kc) {
      const int kb = kc*32 + kq*8;
      bf16x8 bh[NT], bl[NT];
#pragma unroll
      for (int nt = 0; nt < NT; ++nt) {
        const int ro = (nBase + nt*16 + lm)*64 + kb;
        bh[nt] = *(const bf16x8*)(xHi + ro);
        bl[nt] = *(const bf16x8*)(xLo + ro);
      }
#pragma unroll
      for (int mp = 0; mp < 2; ++mp) {
        bf16x8 ah[2], al[2];
#pragma unroll
        for (int i = 0; i < 2; ++i) {          // vector f16 LDS read
          const f16x8 pv = *(const f16x8*)((const _Float16*)pxh + (mBase + (2*mp+i)*16 + lm)*64 + kb);
#pragma unroll
          for (int j = 0; j < 8; ++j) {
            float v = (float)pv[j];
            __bf16 h = (__bf16)v;
            ah[i][j] = h;
            al[i][j] = (__bf16)(v - (float)h);
          }
        }
        __builtin_amdgcn_s_setprio(1);
#pragma unroll
        for (int nt = 0; nt < NT; ++nt) {
          if constexpr (NT <= 2) {
            acc [2*mp  ][nt] = MFMA16(ah[0], bh[nt], acc [2*mp  ][nt]);
            acc [2*mp+1][nt] = MFMA16(ah[1], bh[nt], acc [2*mp+1][nt]);
            accQ[2*mp  ][nt] = MFMA16(ah[0], bl[nt], accQ[2*mp  ][nt]);
            accQ[2*mp+1][nt] = MFMA16(ah[1], bl[nt], accQ[2*mp+1][nt]);
            accQ[2*mp  ][nt] = MFMA16(al[0], bh[nt], accQ[2*mp  ][nt]);
            accQ[2*mp+1][nt] = MFMA16(al[1], bh[nt], accQ[2*mp+1][nt]);
          } else {
            acc[2*mp  ][nt] = MFMA16(ah[0], bh[nt], acc[2*mp  ][nt]);
            acc[2*mp+1][nt] = MFMA16(ah[1], bh[nt], acc[2*mp+1][nt]);
            acc[2*mp  ][nt] = MFMA16(ah[0], bl[nt], acc[2*mp  ][nt]);
            acc[2*mp+1][nt] = MFMA16(ah[1], bl[nt], acc[2*mp+1][nt]);
            acc[2*mp  ][nt] = MFMA16(al[0], bh[nt], acc[2*mp  ][nt]);
            acc[2*mp+1][nt] = MFMA16(al[1], bh[nt], acc[2*mp+1][nt]);
          }
        }
        __builtin_amdgcn_s_setprio(0);
      }
    }
  }
  __syncthreads();                 // all reads of act complete
#pragma unroll
  for (int mt = 0; mt < 4; ++mt)
#pragma unroll
    for (int nt = 0; nt < NT; ++nt) {
      const int col = nBase + nt*16 + lm;
      float bv = bias[col] + (pdW ? pdW[col] : 0.f);
#pragma unroll
      for (int r = 0; r < 4; ++r) {
        const int row = mBase + mt*16 + kq*4 + r;
        float v = acc[mt][nt][r];
        if constexpr (NT <= 2) v += accQ[mt][nt][r];
        v += bv;
        if (relu) v = fmaxf(v, 0.f);
        __bf16 h = (__bf16)v;
        aHi[row*AH + col] = h;
        aLo[row*AH + col] = (__bf16)(v - (float)h);
      }
    }
  __syncthreads();
}

// HALF=1: blockIdx = ray*2 + half, covers samples [half*64, half*64+64)
// HALF=0: blockIdx = ray, covers all 128 samples (fallback config)
template<int HALF>
__global__ __launch_bounds__(512, 4)
void nerf_main(
    const float* __restrict__ ro, const float* __restrict__ rd, const float* __restrict__ tin,
    const float* __restrict__ b0, const float* __restrict__ bh,
    const float* __restrict__ b5, const float* __restrict__ b6,
    const float* __restrict__ b7,
    const float* __restrict__ Wsig, const float* __restrict__ bs,
    const float* __restrict__ bfb,
    const float* __restrict__ Wm, const float* __restrict__ bm,
    const float* __restrict__ Wr, const float* __restrict__ br,
    const __bf16* __restrict__ wsHi, const __bf16* __restrict__ wsLo,
    float* __restrict__ part, float* __restrict__ out) {
  constexpr int M = HALF ? 64 : 128;
  __shared__ __align__(16) __bf16 aHi[M * AH];
  __shared__ __align__(16) __bf16 aLo[M * AH];
  __shared__ __align__(16) unsigned char pxred[M * 128];  // pxh (M*64 halves) / red union
  __shared__ __align__(16) float  pdBuf[24];
  __shared__ __align__(16) float  pdW[128];
  __shared__ __align__(16) float  tBuf[M + 4];
  __shared__ __align__(16) float  sigBuf[M];
  __shared__ __align__(16) float  rgbBuf[M * 3];

  __half* pxh = (__half*)pxred;
  float*  red = (float*)pxred;         // used after pxh dead (sigma head onward)

  const int blk  = blockIdx.x;
  const int ray  = HALF ? (blk >> 1) : blk;
  const int S    = HALF ? (blk & 1) * 64 : 0;
  const int tid  = threadIdx.x;

  // ---- positional encodings ----
  if (tid < M) {
    const int m = tid;
    float tv = tin[ray*128 + S + m];
    tBuf[m] = tv;
    float xs[3];
#pragma unroll
    for (int c = 0; c < 3; ++c) xs[c] = ro[ray*3 + c] + tv * rd[ray*3 + c];
#pragma unroll
    for (int i = 0; i < 10; ++i)
#pragma unroll
      for (int c = 0; c < 3; ++c) {
        float a = ldexpf(xs[c], i);                 // sin(2^i*pi*x) = sinpi(2^i*x)
        pxh[m*64 + i*6 + c]     = __float2half(sinpif(a));
        pxh[m*64 + i*6 + 3 + c] = __float2half(cospif(a));
      }
#pragma unroll
    for (int j = 60; j < 64; ++j) pxh[m*64 + j] = __float2half(0.f);
  } else if (tid < M + 24) {
    int j = tid - M;
    int i = j / 6, r = j % 6;
    float a = ldexpf(rd[ray*3 + (r % 3)], i);
    pdBuf[j] = (r < 3) ? sinpif(a) : cospif(a);
  } else if (tid == M + 24) {
    tBuf[M] = (S + M < 128) ? tin[ray*128 + S + M] : 0.f;   // next-t for last delta
  }
  __syncthreads();
  if (tid >= 256 && tid < 384) {       // pdW[c] = sum_j pd[j]*Wm[256+j][c]
    int c = tid - 256;
    float s = 0.f;
#pragma unroll
    for (int j = 0; j < 24; ++j) s += pdBuf[j] * Wm[(256 + j)*128 + c];
    pdW[c] = s;
  }
  __syncthreads();

  constexpr int NTF = HALF ? 2 : 4;    // full layers (N=256)
  constexpr int NTW = HALF ? 1 : 2;    // Wm layer (N=128)

  // ---- trunk ----
  mfma_layer<NTF, HALF>(aHi, aLo, pxh, nullptr, nullptr, 0, 0,
                        wsHi + OFF_W0T, wsLo + OFF_W0T, b0, nullptr, true, tid);
  for (int i = 0; i < 4; ++i)
    mfma_layer<NTF, HALF>(aHi, aLo, pxh, wsHi + OFF_WHT + i*65536, wsLo + OFF_WHT + i*65536, 256, 8,
                          nullptr, nullptr, bh + i*256, nullptr, true, tid);
  mfma_layer<NTF, HALF>(aHi, aLo, pxh, wsHi + OFF_W5AT, wsLo + OFF_W5AT, 256, 8,
                        wsHi + OFF_W5BT, wsLo + OFF_W5BT, b5, nullptr, true, tid);
  mfma_layer<NTF, HALF>(aHi, aLo, pxh, wsHi + OFF_W6T, wsLo + OFF_W6T, 256, 8,
                        nullptr, nullptr, b6, nullptr, true, tid);
  mfma_layer<NTF, HALF>(aHi, aLo, pxh, wsHi + OFF_W7T, wsLo + OFF_W7T, 256, 8,
                        nullptr, nullptr, b7, nullptr, true, tid);

  // sigma = relu(h @ Ws + bs)   (pxh now dead -> red)
  {
    constexpr int TPS = 512 / M;       // threads per sample (8 or 4)
    const int m = tid / TPS, q = tid % TPS;
    const int kn = 256 / TPS;
    float s = 0.f;
    for (int k8 = q*kn; k8 < q*kn + kn; k8 += 8) {
      bf16x8 vh = *(const bf16x8*)(aHi + m*AH + k8);
      bf16x8 vl = *(const bf16x8*)(aLo + m*AH + k8);
#pragma unroll
      for (int j = 0; j < 8; ++j) s += ((float)vh[j] + (float)vl[j]) * Wsig[k8 + j];
    }
    red[tid] = s;
    __syncthreads();
    if (tid < M) {
      float sm = bs[0];
#pragma unroll
      for (int j = 0; j < TPS; ++j) sm += red[TPS*tid + j];
      sigBuf[tid] = fmaxf(sm, 0.f);
    }
    __syncthreads();
  }

  // feat = h @ Wf + bf (no relu)
  mfma_layer<NTF, HALF>(aHi, aLo, nullptr, wsHi + OFF_WFT, wsLo + OFF_WFT, 256, 8,
                        nullptr, nullptr, bfb, nullptr, false, tid);

  // h2 = relu([feat, pd] @ Wm + bm), N=128 (pd folded via pdW)
  mfma_layer<NTW, HALF>(aHi, aLo, nullptr, wsHi + OFF_WMAT, wsLo + OFF_WMAT, 256, 8,
                        nullptr, nullptr, bm, pdW, true, tid);

  // rgb = sigmoid(h2 @ Wr + br)
  {
    constexpr int TPS = 512 / M;
    const int m = tid / TPS, q = tid % TPS;
    const int kn = 128 / TPS;
    float r0s = 0.f, r1s = 0.f, r2s = 0.f;
    for (int k8 = q*kn; k8 < q*kn + kn; k8 += 8) {
      bf16x8 vh = *(const bf16x8*)(aHi + m*AH + k8);
      bf16x8 vl = *(const bf16x8*)(aLo + m*AH + k8);
#pragma unroll
      for (int j = 0; j < 8; ++j) {
        float hv = (float)vh[j] + (float)vl[j];
        r0s += hv * Wr[(k8 + j)*3 + 0];
        r1s += hv * Wr[(k8 + j)*3 + 1];
        r2s += hv * Wr[(k8 + j)*3 + 2];
      }
    }
    red[tid] = r0s; red[512 + tid] = r1s; red[1024 + tid] = r2s;
    __syncthreads();
    if (tid < M) {
#pragma unroll
      for (int c = 0; c < 3; ++c) {
        float sm = br[c];
#pragma unroll
        for (int j = 0; j < TPS; ++j) sm += red[c*512 + TPS*tid + j];
        rgbBuf[tid*3 + c] = 1.f / (1.f + expf(-sm));
      }
    }
    __syncthreads();
  }

  // volume rendering: serial transmittance scan over this block's segment
  if (tid == 0) {
    float T = 1.f, c0 = 0.f, c1 = 0.f, c2 = 0.f, wsum = 0.f;
    for (int m = 0; m < M; ++m) {
      float delta = (S + m < 127) ? (tBuf[m + 1] - tBuf[m]) : 1e8f;
      float e = expf(-sigBuf[m] * delta);
      float w = T * (1.f - e);
      c0 += w * rgbBuf[m*3 + 0];
      c1 += w * rgbBuf[m*3 + 1];
      c2 += w * rgbBuf[m*3 + 2];
      wsum += w;
      T *= e;
    }
    if (HALF) {
      float* p = part + blk*5;
      p[0] = c0; p[1] = c1; p[2] = c2; p[3] = wsum; p[4] = T;
    } else {
      float bg = 1.f - wsum;           // C_BG = (1,1,1)
      out[ray*3 + 0] = c0 + bg;
      out[ray*3 + 1] = c1 + bg;
      out[ray*3 + 2] = c2 + bg;
    }
  }
}

__global__ void combine(const float* __restrict__ part, float* __restrict__ out) {
  int r = blockIdx.x * blockDim.x + threadIdx.x;
  if (r >= 2048) return;
  const float* p0 = part + (2*r)*5;
  const float* p1 = p0 + 5;
  float T0 = p0[4];
  float wsum = p0[3] + T0 * p1[3];
  float bg = 1.f - wsum;               // C_BG = (1,1,1)
#pragma unroll
  for (int c = 0; c < 3; ++c)
    out[r*3 + c] = p0[c] + T0 * p1[c] + bg;
}

extern "C" void kernel_launch(void* const* d_in, const int* in_sizes, int n_in,
                              void* d_out, int out_size, void* d_ws, size_t ws_size,
                              hipStream_t stream) {
  const float* ro  = (const float*)d_in[0];
  const float* rd  = (const float*)d_in[1];
  const float* t   = (const float*)d_in[2];
  const float* W0  = (const float*)d_in[3];
  const float* b0  = (const float*)d_in[4];
  const float* Wh  = (const float*)d_in[5];
  const float* bh  = (const float*)d_in[6];
  const float* W5  = (const float*)d_in[7];
  const float* b5  = (const float*)d_in[8];
  const float* W6  = (const float*)d_in[9];
  const float* b6  = (const float*)d_in[10];
  const float* W7  = (const float*)d_in[11];
  const float* b7  = (const float*)d_in[12];
  const float* Wsg = (const float*)d_in[13];
  const float* bs  = (const float*)d_in[14];
  const float* Wf  = (const float*)d_in[15];
  const float* bfb = (const float*)d_in[16];
  const float* Wm  = (const float*)d_in[17];
  const float* bm  = (const float*)d_in[18];
  const float* Wr  = (const float*)d_in[19];
  const float* br  = (const float*)d_in[20];
  float* out = (float*)d_out;

  __bf16* wsHi = (__bf16*)d_ws;                     // 2*TOT bf16 = 2.36 MB (proven)
  __bf16* wsLo = wsHi + TOT;
  float*  part = (float*)((char*)d_ws + (size_t)2 * TOT * 2);   // 4096*5 floats = 80 KB

  const size_t needSplit = (size_t)2 * TOT * 2 + (size_t)4096 * 5 * 4;

  prep_weights<<<(TOT + 255)/256, 256, 0, stream>>>(W0, Wh, W5, W6, W7, Wf, Wm, wsHi);
  if (ws_size >= needSplit) {
    nerf_main<1><<<4096, 512, 0, stream>>>(ro, rd, t, b0, bh, b5, b6, b7,
                                           Wsg, bs, bfb, Wm, bm, Wr, br,
                                           wsHi, wsLo, part, out);
    combine<<<8, 256, 0, stream>>>(part, out);
  } else {
    nerf_main<0><<<2048, 512, 0, stream>>>(ro, rd, t, b0, bh, b5, b6, b7,
                                           Wsg, bs, bfb, Wm, bm, Wr, br,
                                           wsHi, wsLo, part, out);
  }
}

// Round 13
// 1262.021 us; speedup vs baseline: 1.0460x; 1.0409x over previous
//
#include <hip/hip_runtime.h>
#include <hip/hip_fp16.h>
#include <math.h>

typedef __bf16   bf16x8 __attribute__((ext_vector_type(8)));
typedef _Float16 f16x8  __attribute__((ext_vector_type(8)));
typedef float    f32x4  __attribute__((ext_vector_type(4)));

#define AH  264              // act plane stride (bf16)
#define TOT 589824           // staged weight elems (hi); lo at +TOT

// staged ws layout (bf16, [n][k] transposed, zero-padded K tails)
#define OFF_W0T   0          // [256][64]
#define OFF_WHT   16384      // 4 x [256][256]
#define OFF_W5AT  278528     // [256][256]
#define OFF_W5BT  344064     // [256][64]
#define OFF_W6T   360448     // [256][256]
#define OFF_W7T   425984     // [256][256]
#define OFF_WFT   491520     // [256][256]
#define OFF_WMAT  557056     // [128][256]

__global__ void prep_weights(const float* __restrict__ W0, const float* __restrict__ Wh,
                             const float* __restrict__ W5, const float* __restrict__ W6,
                             const float* __restrict__ W7, const float* __restrict__ Wf,
                             const float* __restrict__ Wm, __bf16* __restrict__ ws) {
  int idx = blockIdx.x * blockDim.x + threadIdx.x;
  if (idx >= TOT) return;
  float v = 0.f;
  if (idx < OFF_WHT)        { int j = idx;            int n=j>>6, k=j&63;   v = (k<60)? W0[k*256+n] : 0.f; }
  else if (idx < OFF_W5AT)  { int j = idx - OFF_WHT;  int i=j>>16, r=j&65535, n=r>>8, k=r&255; v = Wh[i*65536+k*256+n]; }
  else if (idx < OFF_W5BT)  { int j = idx - OFF_W5AT; int n=j>>8, k=j&255;  v = W5[k*256+n]; }
  else if (idx < OFF_W6T)   { int j = idx - OFF_W5BT; int n=j>>6, k=j&63;   v = (k<60)? W5[(256+k)*256+n] : 0.f; }
  else if (idx < OFF_W7T)   { int j = idx - OFF_W6T;  int n=j>>8, k=j&255;  v = W6[k*256+n]; }
  else if (idx < OFF_WFT)   { int j = idx - OFF_W7T;  int n=j>>8, k=j&255;  v = W7[k*256+n]; }
  else if (idx < OFF_WMAT)  { int j = idx - OFF_WFT;  int n=j>>8, k=j&255;  v = Wf[k*256+n]; }
  else                      { int j = idx - OFF_WMAT; int n=j>>8, k=j&255;  v = Wm[k*128+n]; }
  __bf16 hi = (__bf16)v;
  ws[idx] = hi;
  ws[TOT + idx] = (__bf16)(v - (float)hi);
}

#define MFMA16(A,B,C) __builtin_amdgcn_mfma_f32_16x16x32_bf16((A),(B),(C),0,0,0)

// ---- split-bf16 3-pass MFMA layer; act = hi/lo bf16 planes in LDS ----
// CHAMPION (R10, 1255 us): R3 structure + setprio. 512 threads = 8 waves,
// 4 m-tiles per wave, HALF=1: M=64, mBase=0, nBase=wave*(NT*16). NT<=2 path:
// explicit A/B weight double-buffer -- the ONLY register-feasible pipelining
// shape (ledger: no-dbuf R5/R8 exposed L2 latency; NT=4 dbuf R6/R7 spilled;
// M=32 R9 doubled fixed-latency fraction; 32x32 MFMA R11 deepened dep chains;
// dual-acc R12 spilled). Compiler pins ~64 arch VGPRs in all configs.
// Accumulation order per acc element: kc ascending; a_h*b_h, a_h*b_l, a_l*b_h
// -> bit-identical numerics to all prior versions.
template<int NT, int HALF>
__device__ __forceinline__ void mfma_layer(__bf16* aHi, __bf16* aLo, const __half* pxh,
    const __bf16* __restrict__ wHi, const __bf16* __restrict__ wLo, int kStr, int nkc,
    const __bf16* __restrict__ xHi, const __bf16* __restrict__ xLo,  // px weights or null
    const float* __restrict__ bias, const float* __restrict__ pdW,
    bool relu, int tid) {
  const int wave = tid >> 6, lane = tid & 63;
  const int lm = lane & 15, kq = lane >> 4;
  const int mBase = HALF ? 0 : (wave >> 2) * 64;
  const int nBase = (HALF ? wave : (wave & 3)) * (NT * 16);
  f32x4 acc[4][NT];
#pragma unroll
  for (int mt = 0; mt < 4; ++mt)
#pragma unroll
    for (int nt = 0; nt < NT; ++nt)
#pragma unroll
      for (int e = 0; e < 4; ++e) acc[mt][nt][e] = 0.f;

  if (nkc >= 2) {                              // act part (K = nkc*32, nkc always even)
    if constexpr (NT <= 2) {
      const int kb0 = kq * 8;
      int wr[NT];
#pragma unroll
      for (int nt = 0; nt < NT; ++nt) wr[nt] = (nBase + nt*16 + lm)*kStr + kb0;
      const int ab = (mBase + lm)*AH + kb0;
      bf16x8 bhA[NT], blA[NT], bhB[NT], blB[NT];
#pragma unroll
      for (int nt = 0; nt < NT; ++nt) {        // preload kc=0
        bhA[nt] = *(const bf16x8*)(wHi + wr[nt]);
        blA[nt] = *(const bf16x8*)(wLo + wr[nt]);
      }
      for (int kc = 0; kc < nkc; kc += 2) {
        // prefetch kc+1 weights into B while A computes
#pragma unroll
        for (int nt = 0; nt < NT; ++nt) {
          bhB[nt] = *(const bf16x8*)(wHi + wr[nt] + (kc+1)*32);
          blB[nt] = *(const bf16x8*)(wLo + wr[nt] + (kc+1)*32);
        }
#pragma unroll
        for (int mp = 0; mp < 2; ++mp) {       // compute kc with A
          const int r0 = ab + mp*32*AH + kc*32;
          bf16x8 a0h = *(const bf16x8*)(aHi + r0);
          bf16x8 a0l = *(const bf16x8*)(aLo + r0);
          bf16x8 a1h = *(const bf16x8*)(aHi + r0 + 16*AH);
          bf16x8 a1l = *(const bf16x8*)(aLo + r0 + 16*AH);
          __builtin_amdgcn_s_setprio(1);
#pragma unroll
          for (int nt = 0; nt < NT; ++nt) {
            acc[2*mp  ][nt] = MFMA16(a0h, bhA[nt], acc[2*mp  ][nt]);
            acc[2*mp+1][nt] = MFMA16(a1h, bhA[nt], acc[2*mp+1][nt]);
            acc[2*mp  ][nt] = MFMA16(a0h, blA[nt], acc[2*mp  ][nt]);
            acc[2*mp+1][nt] = MFMA16(a1h, blA[nt], acc[2*mp+1][nt]);
            acc[2*mp  ][nt] = MFMA16(a0l, bhA[nt], acc[2*mp  ][nt]);
            acc[2*mp+1][nt] = MFMA16(a1l, bhA[nt], acc[2*mp+1][nt]);
          }
          __builtin_amdgcn_s_setprio(0);
        }
        if (kc + 2 < nkc) {                    // prefetch kc+2 into A
#pragma unroll
          for (int nt = 0; nt < NT; ++nt) {
            bhA[nt] = *(const bf16x8*)(wHi + wr[nt] + (kc+2)*32);
            blA[nt] = *(const bf16x8*)(wLo + wr[nt] + (kc+2)*32);
          }
        }
#pragma unroll
        for (int mp = 0; mp < 2; ++mp) {       // compute kc+1 with B
          const int r0 = ab + mp*32*AH + (kc+1)*32;
          bf16x8 a0h = *(const bf16x8*)(aHi + r0);
          bf16x8 a0l = *(const bf16x8*)(aLo + r0);
          bf16x8 a1h = *(const bf16x8*)(aHi + r0 + 16*AH);
          bf16x8 a1l = *(const bf16x8*)(aLo + r0 + 16*AH);
          __builtin_amdgcn_s_setprio(1);
#pragma unroll
          for (int nt = 0; nt < NT; ++nt) {
            acc[2*mp  ][nt] = MFMA16(a0h, bhB[nt], acc[2*mp  ][nt]);
            acc[2*mp+1][nt] = MFMA16(a1h, bhB[nt], acc[2*mp+1][nt]);
            acc[2*mp  ][nt] = MFMA16(a0h, blB[nt], acc[2*mp  ][nt]);
            acc[2*mp+1][nt] = MFMA16(a1h, blB[nt], acc[2*mp+1][nt]);
            acc[2*mp  ][nt] = MFMA16(a0l, bhB[nt], acc[2*mp  ][nt]);
            acc[2*mp+1][nt] = MFMA16(a1l, bhB[nt], acc[2*mp+1][nt]);
          }
          __builtin_amdgcn_s_setprio(0);
        }
      }
    } else {                                   // NT=4 fallback (unused in HALF=1 runs)
      for (int kc = 0; kc < nkc; ++kc) {
        const int kb = kc*32 + kq*8;
        bf16x8 ah[4], al[4], bh[NT], bl[NT];
#pragma unroll
        for (int mt = 0; mt < 4; ++mt) {
          const int off = (mBase + mt*16 + lm)*AH + kb;
          ah[mt] = *(const bf16x8*)(aHi + off);
          al[mt] = *(const bf16x8*)(aLo + off);
        }
#pragma unroll
        for (int nt = 0; nt < NT; ++nt) {
          const int ro = (nBase + nt*16 + lm)*kStr + kb;
          bh[nt] = *(const bf16x8*)(wHi + ro);
          bl[nt] = *(const bf16x8*)(wLo + ro);
        }
#pragma unroll
        for (int p = 0; p < 3; ++p)
#pragma unroll
          for (int mt = 0; mt < 4; ++mt)
#pragma unroll
            for (int nt = 0; nt < NT; ++nt)
              acc[mt][nt] = __builtin_amdgcn_mfma_f32_16x16x32_bf16(
                  (p == 2) ? al[mt] : ah[mt],
                  (p == 1) ? bl[nt] : bh[nt],
                  acc[mt][nt], 0, 0, 0);
      }
    }
  }
  if (xHi) {                                   // px part, K=64 (zero-padded tail)
#pragma unroll
    for (int kc = 0; kc < 2; ++kc) {
      const int kb = kc*32 + kq*8;
      bf16x8 bh[NT], bl[NT];
#pragma unroll
      for (int nt = 0; nt < NT; ++nt) {
        const int ro = (nBase + nt*16 + lm)*64 + kb;
        bh[nt] = *(const bf16x8*)(xHi + ro);
        bl[nt] = *(const bf16x8*)(xLo + ro);
      }
#pragma unroll
      for (int mp = 0; mp < 2; ++mp) {
        bf16x8 ah[2], al[2];
#pragma unroll
        for (int i = 0; i < 2; ++i) {          // vector f16 LDS read
          const f16x8 pv = *(const f16x8*)((const _Float16*)pxh + (mBase + (2*mp+i)*16 + lm)*64 + kb);
#pragma unroll
          for (int j = 0; j < 8; ++j) {
            float v = (float)pv[j];
            __bf16 h = (__bf16)v;
            ah[i][j] = h;
            al[i][j] = (__bf16)(v - (float)h);
          }
        }
        __builtin_amdgcn_s_setprio(1);
#pragma unroll
        for (int nt = 0; nt < NT; ++nt) {
          acc[2*mp  ][nt] = MFMA16(ah[0], bh[nt], acc[2*mp  ][nt]);
          acc[2*mp+1][nt] = MFMA16(ah[1], bh[nt], acc[2*mp+1][nt]);
          acc[2*mp  ][nt] = MFMA16(ah[0], bl[nt], acc[2*mp  ][nt]);
          acc[2*mp+1][nt] = MFMA16(ah[1], bl[nt], acc[2*mp+1][nt]);
          acc[2*mp  ][nt] = MFMA16(al[0], bh[nt], acc[2*mp  ][nt]);
          acc[2*mp+1][nt] = MFMA16(al[1], bh[nt], acc[2*mp+1][nt]);
        }
        __builtin_amdgcn_s_setprio(0);
      }
    }
  }
  __syncthreads();                 // all reads of act complete
#pragma unroll
  for (int mt = 0; mt < 4; ++mt)
#pragma unroll
    for (int nt = 0; nt < NT; ++nt) {
      const int col = nBase + nt*16 + lm;
      float bv = bias[col] + (pdW ? pdW[col] : 0.f);
#pragma unroll
      for (int r = 0; r < 4; ++r) {
        const int row = mBase + mt*16 + kq*4 + r;
        float v = acc[mt][nt][r] + bv;
        if (relu) v = fmaxf(v, 0.f);
        __bf16 h = (__bf16)v;
        aHi[row*AH + col] = h;
        aLo[row*AH + col] = (__bf16)(v - (float)h);
      }
    }
  __syncthreads();
}

// HALF=1: blockIdx = ray*2 + half, covers samples [half*64, half*64+64)
// HALF=0: blockIdx = ray, covers all 128 samples (fallback config)
template<int HALF>
__global__ __launch_bounds__(512, 4)
void nerf_main(
    const float* __restrict__ ro, const float* __restrict__ rd, const float* __restrict__ tin,
    const float* __restrict__ b0, const float* __restrict__ bh,
    const float* __restrict__ b5, const float* __restrict__ b6,
    const float* __restrict__ b7,
    const float* __restrict__ Wsig, const float* __restrict__ bs,
    const float* __restrict__ bfb,
    const float* __restrict__ Wm, const float* __restrict__ bm,
    const float* __restrict__ Wr, const float* __restrict__ br,
    const __bf16* __restrict__ wsHi, const __bf16* __restrict__ wsLo,
    float* __restrict__ part, float* __restrict__ out) {
  constexpr int M = HALF ? 64 : 128;
  __shared__ __align__(16) __bf16 aHi[M * AH];
  __shared__ __align__(16) __bf16 aLo[M * AH];
  __shared__ __align__(16) unsigned char pxred[M * 128];  // pxh (M*64 halves) / red union
  __shared__ __align__(16) float  pdBuf[24];
  __shared__ __align__(16) float  pdW[128];
  __shared__ __align__(16) float  tBuf[M + 4];
  __shared__ __align__(16) float  sigBuf[M];
  __shared__ __align__(16) float  rgbBuf[M * 3];

  __half* pxh = (__half*)pxred;
  float*  red = (float*)pxred;         // used after pxh dead (sigma head onward)

  const int blk  = blockIdx.x;
  const int ray  = HALF ? (blk >> 1) : blk;
  const int S    = HALF ? (blk & 1) * 64 : 0;
  const int tid  = threadIdx.x;

  // ---- positional encodings ----
  if (tid < M) {
    const int m = tid;
    float tv = tin[ray*128 + S + m];
    tBuf[m] = tv;
    float xs[3];
#pragma unroll
    for (int c = 0; c < 3; ++c) xs[c] = ro[ray*3 + c] + tv * rd[ray*3 + c];
#pragma unroll
    for (int i = 0; i < 10; ++i)
#pragma unroll
      for (int c = 0; c < 3; ++c) {
        float a = ldexpf(xs[c], i);                 // sin(2^i*pi*x) = sinpi(2^i*x)
        pxh[m*64 + i*6 + c]     = __float2half(sinpif(a));
        pxh[m*64 + i*6 + 3 + c] = __float2half(cospif(a));
      }
#pragma unroll
    for (int j = 60; j < 64; ++j) pxh[m*64 + j] = __float2half(0.f);
  } else if (tid < M + 24) {
    int j = tid - M;
    int i = j / 6, r = j % 6;
    float a = ldexpf(rd[ray*3 + (r % 3)], i);
    pdBuf[j] = (r < 3) ? sinpif(a) : cospif(a);
  } else if (tid == M + 24) {
    tBuf[M] = (S + M < 128) ? tin[ray*128 + S + M] : 0.f;   // next-t for last delta
  }
  __syncthreads();
  if (tid >= 256 && tid < 384) {       // pdW[c] = sum_j pd[j]*Wm[256+j][c]
    int c = tid - 256;
    float s = 0.f;
#pragma unroll
    for (int j = 0; j < 24; ++j) s += pdBuf[j] * Wm[(256 + j)*128 + c];
    pdW[c] = s;
  }
  __syncthreads();

  constexpr int NTF = HALF ? 2 : 4;    // full layers (N=256)
  constexpr int NTW = HALF ? 1 : 2;    // Wm layer (N=128)

  // ---- trunk ----
  mfma_layer<NTF, HALF>(aHi, aLo, pxh, nullptr, nullptr, 0, 0,
                        wsHi + OFF_W0T, wsLo + OFF_W0T, b0, nullptr, true, tid);
  for (int i = 0; i < 4; ++i)
    mfma_layer<NTF, HALF>(aHi, aLo, pxh, wsHi + OFF_WHT + i*65536, wsLo + OFF_WHT + i*65536, 256, 8,
                          nullptr, nullptr, bh + i*256, nullptr, true, tid);
  mfma_layer<NTF, HALF>(aHi, aLo, pxh, wsHi + OFF_W5AT, wsLo + OFF_W5AT, 256, 8,
                        wsHi + OFF_W5BT, wsLo + OFF_W5BT, b5, nullptr, true, tid);
  mfma_layer<NTF, HALF>(aHi, aLo, pxh, wsHi + OFF_W6T, wsLo + OFF_W6T, 256, 8,
                        nullptr, nullptr, b6, nullptr, true, tid);
  mfma_layer<NTF, HALF>(aHi, aLo, pxh, wsHi + OFF_W7T, wsLo + OFF_W7T, 256, 8,
                        nullptr, nullptr, b7, nullptr, true, tid);

  // sigma = relu(h @ Ws + bs)   (pxh now dead -> red)
  {
    constexpr int TPS = 512 / M;       // threads per sample (8 or 4)
    const int m = tid / TPS, q = tid % TPS;
    const int kn = 256 / TPS;
    float s = 0.f;
    for (int k8 = q*kn; k8 < q*kn + kn; k8 += 8) {
      bf16x8 vh = *(const bf16x8*)(aHi + m*AH + k8);
      bf16x8 vl = *(const bf16x8*)(aLo + m*AH + k8);
#pragma unroll
      for (int j = 0; j < 8; ++j) s += ((float)vh[j] + (float)vl[j]) * Wsig[k8 + j];
    }
    red[tid] = s;
    __syncthreads();
    if (tid < M) {
      float sm = bs[0];
#pragma unroll
      for (int j = 0; j < TPS; ++j) sm += red[TPS*tid + j];
      sigBuf[tid] = fmaxf(sm, 0.f);
    }
    __syncthreads();
  }

  // feat = h @ Wf + bf (no relu)
  mfma_layer<NTF, HALF>(aHi, aLo, nullptr, wsHi + OFF_WFT, wsLo + OFF_WFT, 256, 8,
                        nullptr, nullptr, bfb, nullptr, false, tid);

  // h2 = relu([feat, pd] @ Wm + bm), N=128 (pd folded via pdW)
  mfma_layer<NTW, HALF>(aHi, aLo, nullptr, wsHi + OFF_WMAT, wsLo + OFF_WMAT, 256, 8,
                        nullptr, nullptr, bm, pdW, true, tid);

  // rgb = sigmoid(h2 @ Wr + br)
  {
    constexpr int TPS = 512 / M;
    const int m = tid / TPS, q = tid % TPS;
    const int kn = 128 / TPS;
    float r0s = 0.f, r1s = 0.f, r2s = 0.f;
    for (int k8 = q*kn; k8 < q*kn + kn; k8 += 8) {
      bf16x8 vh = *(const bf16x8*)(aHi + m*AH + k8);
      bf16x8 vl = *(const bf16x8*)(aLo + m*AH + k8);
#pragma unroll
      for (int j = 0; j < 8; ++j) {
        float hv = (float)vh[j] + (float)vl[j];
        r0s += hv * Wr[(k8 + j)*3 + 0];
        r1s += hv * Wr[(k8 + j)*3 + 1];
        r2s += hv * Wr[(k8 + j)*3 + 2];
      }
    }
    red[tid] = r0s; red[512 + tid] = r1s; red[1024 + tid] = r2s;
    __syncthreads();
    if (tid < M) {
#pragma unroll
      for (int c = 0; c < 3; ++c) {
        float sm = br[c];
#pragma unroll
        for (int j = 0; j < TPS; ++j) sm += red[c*512 + TPS*tid + j];
        rgbBuf[tid*3 + c] = 1.f / (1.f + expf(-sm));
      }
    }
    __syncthreads();
  }

  // volume rendering: serial transmittance scan over this block's segment
  if (tid == 0) {
    float T = 1.f, c0 = 0.f, c1 = 0.f, c2 = 0.f, wsum = 0.f;
    for (int m = 0; m < M; ++m) {
      float delta = (S + m < 127) ? (tBuf[m + 1] - tBuf[m]) : 1e8f;
      float e = expf(-sigBuf[m] * delta);
      float w = T * (1.f - e);
      c0 += w * rgbBuf[m*3 + 0];
      c1 += w * rgbBuf[m*3 + 1];
      c2 += w * rgbBuf[m*3 + 2];
      wsum += w;
      T *= e;
    }
    if (HALF) {
      float* p = part + blk*5;
      p[0] = c0; p[1] = c1; p[2] = c2; p[3] = wsum; p[4] = T;
    } else {
      float bg = 1.f - wsum;           // C_BG = (1,1,1)
      out[ray*3 + 0] = c0 + bg;
      out[ray*3 + 1] = c1 + bg;
      out[ray*3 + 2] = c2 + bg;
    }
  }
}

__global__ void combine(const float* __restrict__ part, float* __restrict__ out) {
  int r = blockIdx.x * blockDim.x + threadIdx.x;
  if (r >= 2048) return;
  const float* p0 = part + (2*r)*5;
  const float* p1 = p0 + 5;
  float T0 = p0[4];
  float wsum = p0[3] + T0 * p1[3];
  float bg = 1.f - wsum;               // C_BG = (1,1,1)
#pragma unroll
  for (int c = 0; c < 3; ++c)
    out[r*3 + c] = p0[c] + T0 * p1[c] + bg;
}

extern "C" void kernel_launch(void* const* d_in, const int* in_sizes, int n_in,
                              void* d_out, int out_size, void* d_ws, size_t ws_size,
                              hipStream_t stream) {
  const float* ro  = (const float*)d_in[0];
  const float* rd  = (const float*)d_in[1];
  const float* t   = (const float*)d_in[2];
  const float* W0  = (const float*)d_in[3];
  const float* b0  = (const float*)d_in[4];
  const float* Wh  = (const float*)d_in[5];
  const float* bh  = (const float*)d_in[6];
  const float* W5  = (const float*)d_in[7];
  const float* b5  = (const float*)d_in[8];
  const float* W6  = (const float*)d_in[9];
  const float* b6  = (const float*)d_in[10];
  const float* W7  = (const float*)d_in[11];
  const float* b7  = (const float*)d_in[12];
  const float* Wsg = (const float*)d_in[13];
  const float* bs  = (const float*)d_in[14];
  const float* Wf  = (const float*)d_in[15];
  const float* bfb = (const float*)d_in[16];
  const float* Wm  = (const float*)d_in[17];
  const float* bm  = (const float*)d_in[18];
  const float* Wr  = (const float*)d_in[19];
  const float* br  = (const float*)d_in[20];
  float* out = (float*)d_out;

  __bf16* wsHi = (__bf16*)d_ws;                     // 2*TOT bf16 = 2.36 MB (proven)
  __bf16* wsLo = wsHi + TOT;
  float*  part = (float*)((char*)d_ws + (size_t)2 * TOT * 2);   // 4096*5 floats = 80 KB

  const size_t needSplit = (size_t)2 * TOT * 2 + (size_t)4096 * 5 * 4;

  prep_weights<<<(TOT + 255)/256, 256, 0, stream>>>(W0, Wh, W5, W6, W7, Wf, Wm, wsHi);
  if (ws_size >= needSplit) {
    nerf_main<1><<<4096, 512, 0, stream>>>(ro, rd, t, b0, bh, b5, b6, b7,
                                           Wsg, bs, bfb, Wm, bm, Wr, br,
                                           wsHi, wsLo, part, out);
    combine<<<8, 256, 0, stream>>>(part, out);
  } else {
    nerf_main<0><<<2048, 512, 0, stream>>>(ro, rd, t, b0, bh, b5, b6, b7,
                                           Wsg, bs, bfb, Wm, bm, Wr, br,
                                           wsHi, wsLo, part, out);
  }
}